// Round 1
// baseline (319.216 us; speedup 1.0000x reference)
//
#include <hip/hip_runtime.h>

#define B_ 2
#define C_ 3
#define H_ 512
#define W_ 512
#define F_ 5
#define T_ 25

__global__ __launch_bounds__(256) void dsepconv_kernel(
    const float* __restrict__ inp,
    const float* __restrict__ vert,
    const float* __restrict__ horz,
    const float* __restrict__ offx,
    const float* __restrict__ offy,
    const float* __restrict__ mask,
    float* __restrict__ out)
{
    int idx = blockIdx.x * blockDim.x + threadIdx.x;
    if (idx >= B_ * H_ * W_) return;
    int w = idx % W_;
    int h = (idx / W_) % H_;
    int b = idx / (H_ * W_);

    const int hw = h * W_ + w;
    const size_t HW = (size_t)H_ * W_;

    // preload separable filter values for this pixel
    const float* vb = vert + (size_t)b * F_ * HW + hw;
    const float* hb = horz + (size_t)b * F_ * HW + hw;
    float v[F_], hz[F_];
#pragma unroll
    for (int f = 0; f < F_; ++f) {
        v[f]  = vb[f * HW];
        hz[f] = hb[f * HW];
    }

    const float* ob_x = offx + (size_t)b * T_ * HW + hw;
    const float* ob_y = offy + (size_t)b * T_ * HW + hw;
    const float* mb   = mask + (size_t)b * T_ * HW + hw;
    const float* ib   = inp  + (size_t)b * C_ * HW;

    float acc0 = 0.f, acc1 = 0.f, acc2 = 0.f;

    const float wf = (float)w;
    const float hf = (float)h;

#pragma unroll
    for (int t = 0; t < T_; ++t) {
        const int fy = t / F_;
        const int fx = t % F_;
        float oy = ob_y[t * HW];
        float ox = ob_x[t * HW];
        float m  = mb[t * HW];

        // faithful to reference: x coord uses offset_y, y coord uses offset_x
        float xn = 2.0f * (oy + wf + (float)fx - 2.0f + 1.0f) / (float)W_ - 1.0f;
        float yn = 2.0f * (ox + hf + (float)fy - 2.0f + 1.0f) / (float)H_ - 1.0f;
        xn = fminf(fmaxf(xn, -1.0f), 1.0f);
        yn = fminf(fmaxf(yn, -1.0f), 1.0f);
        float ixf = ((xn + 1.0f) * (float)W_ - 1.0f) * 0.5f;
        float iyf = ((yn + 1.0f) * (float)H_ - 1.0f) * 0.5f;

        float x0f = floorf(ixf), y0f = floorf(iyf);
        float wx1 = ixf - x0f,   wy1 = iyf - y0f;
        float wx0 = 1.0f - wx1,  wy0 = 1.0f - wy1;

        int x0 = min(max((int)x0f, 0), W_ - 1);
        int x1 = min(max((int)x0f + 1, 0), W_ - 1);
        int y0 = min(max((int)y0f, 0), H_ - 1);
        int y1 = min(max((int)y0f + 1, 0), H_ - 1);

        float coef = v[fy] * hz[fx] * m;
        float c00 = coef * wy0 * wx0;
        float c01 = coef * wy0 * wx1;
        float c10 = coef * wy1 * wx0;
        float c11 = coef * wy1 * wx1;

        int i00 = y0 * W_ + x0;
        int i01 = y0 * W_ + x1;
        int i10 = y1 * W_ + x0;
        int i11 = y1 * W_ + x1;

        const float* p0 = ib;
        const float* p1 = ib + HW;
        const float* p2 = ib + 2 * HW;
        acc0 += c00 * p0[i00] + c01 * p0[i01] + c10 * p0[i10] + c11 * p0[i11];
        acc1 += c00 * p1[i00] + c01 * p1[i01] + c10 * p1[i10] + c11 * p1[i11];
        acc2 += c00 * p2[i00] + c01 * p2[i01] + c10 * p2[i10] + c11 * p2[i11];
    }

    float* ob = out + (size_t)b * C_ * HW + hw;
    ob[0]      = acc0;
    ob[HW]     = acc1;
    ob[2 * HW] = acc2;
}

extern "C" void kernel_launch(void* const* d_in, const int* in_sizes, int n_in,
                              void* d_out, int out_size, void* d_ws, size_t ws_size,
                              hipStream_t stream) {
    const float* inp  = (const float*)d_in[0];
    const float* vert = (const float*)d_in[1];
    const float* horz = (const float*)d_in[2];
    const float* offx = (const float*)d_in[3];
    const float* offy = (const float*)d_in[4];
    const float* mask = (const float*)d_in[5];
    float* out = (float*)d_out;

    const int total = B_ * H_ * W_;
    dim3 grid((total + 255) / 256), block(256);
    hipLaunchKernelGGL(dsepconv_kernel, grid, block, 0, stream,
                       inp, vert, horz, offx, offy, mask, out);
}

// Round 2
// 262.074 us; speedup vs baseline: 1.2180x; 1.2180x over previous
//
#include <hip/hip_runtime.h>

#define B_ 2
#define C_ 3
#define H_ 512
#define W_ 512
#define F_ 5
#define T_ 25
#define HW_ (H_ * W_)

// streaming loads: no reuse, keep them out of the way of the cached input
#define NT(p) __builtin_nontemporal_load(p)

__global__ __launch_bounds__(256) void dsepconv_kernel(
    const float* __restrict__ inp,
    const float* __restrict__ vert,
    const float* __restrict__ horz,
    const float* __restrict__ offx,
    const float* __restrict__ offy,
    const float* __restrict__ mask,
    float* __restrict__ out)
{
    const int idx = blockIdx.x * blockDim.x + threadIdx.x;  // grid is exact
    const int w = idx & (W_ - 1);
    const int h = (idx >> 9) & (H_ - 1);
    const int b = idx >> 18;

    const int hw = (h << 9) | w;

    // preload separable filter values for this pixel
    const float* vb = vert + b * (F_ * HW_) + hw;
    const float* hb = horz + b * (F_ * HW_) + hw;
    float v[F_], hz[F_];
#pragma unroll
    for (int f = 0; f < F_; ++f) {
        v[f]  = NT(vb + f * HW_);
        hz[f] = NT(hb + f * HW_);
    }

    const float* ob_x = offx + b * (T_ * HW_) + hw;
    const float* ob_y = offy + b * (T_ * HW_) + hw;
    const float* mb   = mask + b * (T_ * HW_) + hw;
    const float* p0   = inp  + b * (C_ * HW_);
    const float* p1   = p0 + HW_;
    const float* p2   = p0 + 2 * HW_;

    float acc0 = 0.f, acc1 = 0.f, acc2 = 0.f;

    const float wf = (float)w;
    const float hf = (float)h;

    // ---- software pipeline over fy rows: prefetch row fy+1 while computing fy ----
    float cy[F_], cx[F_], cm[F_];
#pragma unroll
    for (int fx = 0; fx < F_; ++fx) {
        cy[fx] = NT(ob_y + fx * HW_);
        cx[fx] = NT(ob_x + fx * HW_);
        cm[fx] = NT(mb   + fx * HW_);
    }

#pragma unroll
    for (int fy = 0; fy < F_; ++fy) {
        float ny[F_], nx[F_], nm[F_];
        if (fy < F_ - 1) {
#pragma unroll
            for (int fx = 0; fx < F_; ++fx) {
                const int t = (fy + 1) * F_ + fx;
                ny[fx] = NT(ob_y + t * HW_);
                nx[fx] = NT(ob_x + t * HW_);
                nm[fx] = NT(mb   + t * HW_);
            }
        }

        const float vfy = v[fy];
        const float fyf = (float)fy;

#pragma unroll
        for (int fx = 0; fx < F_; ++fx) {
            const float oy = cy[fx];
            const float ox = cx[fx];
            const float m  = cm[fx];

            // faithful to reference: x coord uses offset_y, y coord uses offset_x
            float xn = 2.0f * (oy + wf + (float)fx - 2.0f + 1.0f) / (float)W_ - 1.0f;
            float yn = 2.0f * (ox + hf + fyf       - 2.0f + 1.0f) / (float)H_ - 1.0f;
            xn = fminf(fmaxf(xn, -1.0f), 1.0f);
            yn = fminf(fmaxf(yn, -1.0f), 1.0f);
            float ixf = ((xn + 1.0f) * (float)W_ - 1.0f) * 0.5f;
            float iyf = ((yn + 1.0f) * (float)H_ - 1.0f) * 0.5f;

            float x0f = floorf(ixf), y0f = floorf(iyf);
            float wx1 = ixf - x0f,   wy1 = iyf - y0f;
            float wx0 = 1.0f - wx1,  wy0 = 1.0f - wy1;

            int x0 = min(max((int)x0f, 0), W_ - 1);
            int x1 = min(max((int)x0f + 1, 0), W_ - 1);
            int y0 = min(max((int)y0f, 0), H_ - 1);
            int y1 = min(max((int)y0f + 1, 0), H_ - 1);

            const float coef = vfy * hz[fx] * m;
            const float c00 = coef * wy0 * wx0;
            const float c01 = coef * wy0 * wx1;
            const float c10 = coef * wy1 * wx0;
            const float c11 = coef * wy1 * wx1;

            const int i00 = (y0 << 9) | x0;
            const int i01 = (y0 << 9) | x1;
            const int i10 = (y1 << 9) | x0;
            const int i11 = (y1 << 9) | x1;

            acc0 += c00 * p0[i00] + c01 * p0[i01] + c10 * p0[i10] + c11 * p0[i11];
            acc1 += c00 * p1[i00] + c01 * p1[i01] + c10 * p1[i10] + c11 * p1[i11];
            acc2 += c00 * p2[i00] + c01 * p2[i01] + c10 * p2[i10] + c11 * p2[i11];
        }

        if (fy < F_ - 1) {
#pragma unroll
            for (int fx = 0; fx < F_; ++fx) {
                cy[fx] = ny[fx];
                cx[fx] = nx[fx];
                cm[fx] = nm[fx];
            }
        }
    }

    float* ob = out + b * (C_ * HW_) + hw;
    __builtin_nontemporal_store(acc0, ob);
    __builtin_nontemporal_store(acc1, ob + HW_);
    __builtin_nontemporal_store(acc2, ob + 2 * HW_);
}

extern "C" void kernel_launch(void* const* d_in, const int* in_sizes, int n_in,
                              void* d_out, int out_size, void* d_ws, size_t ws_size,
                              hipStream_t stream) {
    const float* inp  = (const float*)d_in[0];
    const float* vert = (const float*)d_in[1];
    const float* horz = (const float*)d_in[2];
    const float* offx = (const float*)d_in[3];
    const float* offy = (const float*)d_in[4];
    const float* mask = (const float*)d_in[5];
    float* out = (float*)d_out;

    const int total = B_ * H_ * W_;
    dim3 grid(total / 256), block(256);
    hipLaunchKernelGGL(dsepconv_kernel, grid, block, 0, stream,
                       inp, vert, horz, offx, offy, mask, out);
}